// Round 4
// baseline (255.438 us; speedup 1.0000x reference)
//
#include <hip/hip_runtime.h>

// ExLlama q4: T=32, K=8192, N=28672, group=128.
// Harness promotes fp16 reference arrays to float32; output is float32.
//
// ROUND-4: dur = 135 us fixed ws-poison fills (proven r1) + GEMM + reduce.
// r3 GEMM (68 us): Occupancy 30%, VALU 26%, Mfma 8%, FETCH 66MB (qweight is
// L3-resident) -> stall-bound, occupancy-capped (LDS 33.3KB -> 4 blk/CU;
// ~100 combined V+AGPR). This round raises static occupancy to 20 waves/CU:
//  - LDS exactly 32KB: XOR swizzle (byte ^= (row&7)<<4) instead of +8 pad
//    (row stride 1024B would be 8-way conflict) -> 5 blocks/CU.
//  - reg diet: (scale,const) packed one half2 per (g,j) (16 regs, was 32;
//    broadcasts fold to VOP3P op_sel); launch_bounds(256,5) = 102-reg cap.
//  - qw double-buffer with groups 0 AND 1 prefetched before staging (both
//    land under staging latency; only g2,g3 load during compute), issue
//    pinned with sched_barrier(0) so the allocator can't sink the loads.
//  - fp16 ws: halves GEMM ws writes (57->29MB) + reduce reads (~1e-3 err).
// Verified pieces kept bit-identical: 0x6400 nibble dequant, pkrtz
// pair-permuted x staging, MFMA 16x16x32 f16 fragment mapping.
#define T_TOK   32
#define KDIM    8192
#define NDIM    28672
#define NZW     3584             // N / 8
#define NSEG    16               // K-segments (blockIdx.y)
#define SEGK    (KDIM / NSEG)    // 512
#define GPS     4                // quant groups per segment: SEGK/128
#define XIT     ((T_TOK * SEGK) / (256 * 8))   // 8 staging iters/thread

typedef _Float16 half8  __attribute__((ext_vector_type(8)));
typedef _Float16 half4  __attribute__((ext_vector_type(4)));
typedef _Float16 half2v __attribute__((ext_vector_type(2)));
typedef float    f32x4  __attribute__((ext_vector_type(4)));
typedef unsigned uint4v __attribute__((ext_vector_type(4)));

template<bool ATOMIC>
__global__ __launch_bounds__(256, 5)
void exllama_gemm16(const int*   __restrict__ qweight,
                    const int*   __restrict__ qzeros,
                    const float* __restrict__ scales,
                    const float* __restrict__ x,
                    const float* __restrict__ bias,
                    _Float16*    __restrict__ ws,
                    float*       __restrict__ out)
{
    __shared__ alignas(16) _Float16 xs[T_TOK * SEGK];   // 32768 B exactly
    char* xb = (char*)xs;

    const int tid  = threadIdx.x;
    const int lane = tid & 63;
    const int wav  = tid >> 6;
    const int quad = lane >> 4;
    const int l16  = lane & 15;
    const int seg  = blockIdx.y;
    const int n0   = blockIdx.x * 256 + wav * 64;
    const int g0   = seg * GPS;

    int nc[4];
    #pragma unroll
    for (int j = 0; j < 4; ++j) nc[j] = n0 + j * 16 + l16;

    // ---- group-g qweight tile -> 16 registers (issued early, waited at use)
    auto LOADQW = [&](unsigned* qw, int g) {
        const size_t rb = (size_t)((g0 + g) * 16 + quad) * NDIM;
        #pragma unroll
        for (int c = 0; c < 4; ++c)
            #pragma unroll
            for (int j = 0; j < 4; ++j)
                qw[c * 4 + j] = (unsigned)qweight[rb + (size_t)(c * 4) * NDIM + nc[j]];
    };

    unsigned qwA[16], qwB[16];
    LOADQW(qwA, 0);                       // groups 0 and 1 both in flight
    LOADQW(qwB, 1);                       // before staging: land under it

    // ---- raw scales/zeros for all 4 groups (loads only; convert later) ----
    float sraw[GPS][4];
    int   zraw[GPS][4];
    #pragma unroll
    for (int g = 0; g < GPS; ++g)
        #pragma unroll
        for (int j = 0; j < 4; ++j) {
            sraw[g][j] = scales[(size_t)(g0 + g) * NDIM + nc[j]];
            zraw[g][j] = qzeros[(size_t)(g0 + g) * NZW + (nc[j] >> 3)];
        }

    // ---- stage x segment into LDS as fp16, pair-permuted, XOR-swizzled ----
    {
        const int kseg0 = seg * SEGK;
        #pragma unroll
        for (int it = 0; it < XIT; ++it) {               // 8 iters
            const int e  = it * 2048 + tid * 8;
            const int t  = e >> 9;                       // SEGK = 512
            const int kl = e & (SEGK - 1);
            const float* xp = x + (size_t)t * KDIM + kseg0 + kl;
            f32x4 lo = *(const f32x4*)xp;
            f32x4 hi = *(const f32x4*)(xp + 4);
            uint4v u;
            #pragma unroll
            for (int j = 0; j < 4; ++j)
                u[j] = __builtin_bit_cast(unsigned,
                          __builtin_amdgcn_cvt_pkrtz(lo[j], hi[j]));
            const int off = (t * 1024 + kl * 2) ^ ((t & 7) << 4);
            *(uint4v*)(xb + off) = u;
        }
    }

    // ---- pack (scale, dequant-const) one half2 per (g,j): 16 regs ----
    half2v scp[GPS][4];
    #pragma unroll
    for (int g = 0; g < GPS; ++g)
        #pragma unroll
        for (int j = 0; j < 4; ++j) {
            const int z = (zraw[g][j] >> ((nc[j] & 7) * 4)) & 15;
            scp[g][j] = (half2v){(_Float16)sraw[g][j],
                                 (_Float16)(float)(-(1025 + z))};
        }

    __syncthreads();                       // the ONLY barrier in this kernel

    f32x4 acc[4][2];
    #pragma unroll
    for (int j = 0; j < 4; ++j)
        #pragma unroll
        for (int m = 0; m < 2; ++m)
            acc[j][m] = (f32x4){0.f, 0.f, 0.f, 0.f};

    auto COMPUTEG = [&](const unsigned* qw, int g) {
        #pragma unroll
        for (int c = 0; c < 4; ++c) {
            const int kloc = g * 128 + c * 32 + quad * 8;
            const int o0 = (l16 * 1024 + kloc * 2) ^ ((l16 & 7) << 4);
            half8 a0 = *(const half8*)(xb + o0);
            half8 a1 = *(const half8*)(xb + o0 + 16 * 1024);  // row+16: same key
            #pragma unroll
            for (int j = 0; j < 4; ++j) {
                const unsigned w = qw[c * 4 + j];
                const half2v sc = scp[g][j];
                const half2v s2 = (half2v){sc[0], sc[0]};
                const half2v c2 = (half2v){sc[1], sc[1]};
                uint4v bu;
                #pragma unroll
                for (int i = 0; i < 4; ++i) {
                    unsigned t = ((w >> (4 * i)) & 0x000F000Fu) | 0x64006400u;
                    half2v th = __builtin_bit_cast(half2v, t);
                    half2v r  = (th + c2) * s2;
                    bu[i] = __builtin_bit_cast(unsigned, r);
                }
                half8 bf = __builtin_bit_cast(half8, bu);
                acc[j][0] = __builtin_amdgcn_mfma_f32_16x16x32_f16(a0, bf, acc[j][0], 0, 0, 0);
                acc[j][1] = __builtin_amdgcn_mfma_f32_16x16x32_f16(a1, bf, acc[j][1], 0, 0, 0);
            }
        }
    };

    // ---- compute; g2,g3 prefetched under g1,g2 compute; order pinned ----
    COMPUTEG(qwA, 0);
    LOADQW(qwA, 2);
    __builtin_amdgcn_sched_barrier(0);
    COMPUTEG(qwB, 1);
    LOADQW(qwB, 3);
    __builtin_amdgcn_sched_barrier(0);
    COMPUTEG(qwA, 2);
    COMPUTEG(qwB, 3);

    // ---- epilogue ----
    if (ATOMIC) {
        #pragma unroll
        for (int j = 0; j < 4; ++j) {
            const float bb = bias[nc[j]] * (1.0f / NSEG);
            #pragma unroll
            for (int m = 0; m < 2; ++m)
                #pragma unroll
                for (int r = 0; r < 4; ++r) {
                    const int t = m * 16 + quad * 4 + r;
                    unsafeAtomicAdd(out + (size_t)t * NDIM + nc[j], acc[j][m][r] + bb);
                }
        }
    } else {
        _Float16* wsp = ws + (size_t)seg * (T_TOK * NDIM);
        #pragma unroll
        for (int j = 0; j < 4; ++j)
            #pragma unroll
            for (int m = 0; m < 2; ++m)
                #pragma unroll
                for (int r = 0; r < 4; ++r) {
                    const int t = m * 16 + quad * 4 + r;
                    wsp[(size_t)t * NDIM + nc[j]] = (_Float16)acc[j][m][r];
                }
    }
}

__global__ __launch_bounds__(256)
void reduce_bias(const _Float16* __restrict__ ws,
                 const float*    __restrict__ bias,
                 float*          __restrict__ out)
{
    const int e = (blockIdx.x * 256 + threadIdx.x) * 4;  // 4 consecutive, one row
    const int n = e % NDIM;
    f32x4 sum = (f32x4){0.f, 0.f, 0.f, 0.f};
    #pragma unroll
    for (int s = 0; s < NSEG; ++s) {
        half4 v = *(const half4*)(ws + (size_t)s * (T_TOK * NDIM) + e);
        #pragma unroll
        for (int i = 0; i < 4; ++i) sum[i] += (float)v[i];
    }
    f32x4 bb = *(const f32x4*)(bias + n);
    *(f32x4*)(out + e) = sum + bb;
}

extern "C" void kernel_launch(void* const* d_in, const int* in_sizes, int n_in,
                              void* d_out, int out_size, void* d_ws, size_t ws_size,
                              hipStream_t stream)
{
    const float* x  = (const float*)d_in[0];   // (32, 8192) f32 (fp16 promoted)
    const int* qweight = (const int*)d_in[1];  // (1024, 28672) i32
    const int* qzeros  = (const int*)d_in[2];  // (64, 3584) i32
    const float* sc = (const float*)d_in[3];   // (64, 28672) f32
    const float* bs = (const float*)d_in[4];   // (28672,) f32
    float* out      = (float*)d_out;           // (32, 28672) f32

    const size_t need = (size_t)NSEG * T_TOK * NDIM * sizeof(_Float16);  // 29.4 MB
    if (ws_size >= need) {
        exllama_gemm16<false><<<dim3(NDIM / 256, NSEG), 256, 0, stream>>>(
            qweight, qzeros, sc, x, bs, (_Float16*)d_ws, out);
        reduce_bias<<<(T_TOK * NDIM) / (256 * 4), 256, 0, stream>>>(
            (const _Float16*)d_ws, bs, out);
    } else {
        exllama_gemm16<true><<<dim3(NDIM / 256, NSEG), 256, 0, stream>>>(
            qweight, qzeros, sc, x, bs, nullptr, out);
    }
}

// Round 5
// 198.298 us; speedup vs baseline: 1.2882x; 1.2882x over previous
//
#include <hip/hip_runtime.h>

// ExLlama q4: T=32, K=8192, N=28672, group=128.
// Harness promotes fp16 reference arrays to float32; output is float32.
//
// ROUND-5: r4's launch_bounds(256,5) capped VGPR at 48 -> spills (FETCH
// 105MB/WRITE 100MB of scratch traffic, GEMM 119us). Reverted. Standing
// data: r0 deep-prefetch single-barrier structure = 55us GEMM beats all
// pipelined variants (r2 71, r3 68). Its limiter: 28 waves/CU of work with
// only ~12-16 resident (prologue drains poorly overlapped). This round
// keeps the r0 schedule EXACTLY (whole-segment qweight+scales prefetch
// issued before x staging, ONE barrier, straight-line compute) and doubles
// TLP by halving per-wave columns: 32 cols/wave (grid 224x16), qw prefetch
// 32 regs, acc 16, live ~100 VGPR -> no cap, no spill. Carried from r4
// (correctness-verified there, perf masked by spills): exact-32KB XOR-
// swizzled LDS (byte ^= (t&7)<<4; 5 blocks/CU) and fp16 ws (GEMM writes
// 57->29MB, reduce 10->5.5us).
// Verified pieces bit-identical: 0x6400 nibble dequant, pkrtz pair-permuted
// x staging, MFMA 16x16x32 f16 fragment mapping.
#define T_TOK   32
#define KDIM    8192
#define NDIM    28672
#define NZW     3584             // N / 8
#define NSEG    16               // K-segments (blockIdx.y)
#define SEGK    (KDIM / NSEG)    // 512
#define GPS     4                // quant groups per segment: SEGK/128
#define XIT     ((T_TOK * SEGK) / (256 * 8))   // 8 staging iters/thread

typedef _Float16 half8  __attribute__((ext_vector_type(8)));
typedef float    f32x4  __attribute__((ext_vector_type(4)));
typedef _Float16 half2v __attribute__((ext_vector_type(2)));
typedef unsigned uint4v __attribute__((ext_vector_type(4)));

template<bool ATOMIC>
__global__ __launch_bounds__(256)
void exllama_gemm16(const int*   __restrict__ qweight,
                    const int*   __restrict__ qzeros,
                    const float* __restrict__ scales,
                    const float* __restrict__ x,
                    const float* __restrict__ bias,
                    _Float16*    __restrict__ ws,
                    float*       __restrict__ out)
{
    __shared__ alignas(16) _Float16 xs[T_TOK * SEGK];   // 32768 B exactly
    char* xb = (char*)xs;

    const int tid  = threadIdx.x;
    const int lane = tid & 63;
    const int wav  = tid >> 6;
    const int quad = lane >> 4;
    const int l16  = lane & 15;
    const int seg  = blockIdx.y;
    const int n0   = blockIdx.x * 128 + wav * 32;   // 32 cols per wave
    const int g0   = seg * GPS;

    int nc[2];
    #pragma unroll
    for (int j = 0; j < 2; ++j) nc[j] = n0 + j * 16 + l16;

    // ---- whole-segment qweight prefetch: 32 regs, all in flight before
    //      staging; the staging's counted vmcnt waits absorb the latency ----
    unsigned qw[GPS][8];
    #pragma unroll
    for (int g = 0; g < GPS; ++g) {
        const size_t rb = (size_t)((g0 + g) * 16 + quad) * NDIM;
        #pragma unroll
        for (int c = 0; c < 4; ++c)
            #pragma unroll
            for (int j = 0; j < 2; ++j)
                qw[g][c * 2 + j] = (unsigned)qweight[rb + (size_t)(c * 4) * NDIM + nc[j]];
    }

    // ---- raw scales/zeros for all 4 groups (loads only; convert later) ----
    float sraw[GPS][2];
    int   zraw[GPS][2];
    #pragma unroll
    for (int g = 0; g < GPS; ++g)
        #pragma unroll
        for (int j = 0; j < 2; ++j) {
            sraw[g][j] = scales[(size_t)(g0 + g) * NDIM + nc[j]];
            zraw[g][j] = qzeros[(size_t)(g0 + g) * NZW + (nc[j] >> 3)];
        }

    // ---- stage x segment into LDS as fp16, pair-permuted, XOR-swizzled ----
    {
        const int kseg0 = seg * SEGK;
        #pragma unroll
        for (int it = 0; it < XIT; ++it) {               // 8 iters
            const int e  = it * 2048 + tid * 8;
            const int t  = e >> 9;                       // SEGK = 512
            const int kl = e & (SEGK - 1);
            const float* xp = x + (size_t)t * KDIM + kseg0 + kl;
            f32x4 lo = *(const f32x4*)xp;
            f32x4 hi = *(const f32x4*)(xp + 4);
            uint4v u;
            #pragma unroll
            for (int j = 0; j < 4; ++j)
                u[j] = __builtin_bit_cast(unsigned,
                          __builtin_amdgcn_cvt_pkrtz(lo[j], hi[j]));
            const int off = (t * 1024 + kl * 2) ^ ((t & 7) << 4);
            *(uint4v*)(xb + off) = u;
        }
    }

    // ---- convert scales/zeros (loads landed long ago; no stall) ----
    half2v sp[GPS][2], cp[GPS][2];
    #pragma unroll
    for (int g = 0; g < GPS; ++g)
        #pragma unroll
        for (int j = 0; j < 2; ++j) {
            const int z = (zraw[g][j] >> ((nc[j] & 7) * 4)) & 15;
            const _Float16 sh = (_Float16)sraw[g][j];
            const _Float16 ch = (_Float16)(float)(-(1025 + z));
            sp[g][j] = (half2v){sh, sh};
            cp[g][j] = (half2v){ch, ch};
        }

    __syncthreads();                       // the ONLY barrier in this kernel

    f32x4 acc[2][2];
    #pragma unroll
    for (int j = 0; j < 2; ++j)
        #pragma unroll
        for (int m = 0; m < 2; ++m)
            acc[j][m] = (f32x4){0.f, 0.f, 0.f, 0.f};

    // ---- compute: registers + LDS only, no global traffic ----
    #pragma unroll
    for (int g = 0; g < GPS; ++g) {
        #pragma unroll
        for (int c = 0; c < 4; ++c) {
            const int kloc = g * 128 + c * 32 + quad * 8;
            const int o0 = (l16 * 1024 + kloc * 2) ^ ((l16 & 7) << 4);
            half8 a0 = *(const half8*)(xb + o0);
            half8 a1 = *(const half8*)(xb + o0 + 16 * 1024);  // row+16: same key
            #pragma unroll
            for (int j = 0; j < 2; ++j) {
                const unsigned w = qw[g][c * 2 + j];
                uint4v bu;
                #pragma unroll
                for (int i = 0; i < 4; ++i) {
                    unsigned t = ((w >> (4 * i)) & 0x000F000Fu) | 0x64006400u;
                    half2v th = __builtin_bit_cast(half2v, t);
                    half2v r  = (th + cp[g][j]) * sp[g][j];
                    bu[i] = __builtin_bit_cast(unsigned, r);
                }
                half8 bf = __builtin_bit_cast(half8, bu);
                acc[j][0] = __builtin_amdgcn_mfma_f32_16x16x32_f16(a0, bf, acc[j][0], 0, 0, 0);
                acc[j][1] = __builtin_amdgcn_mfma_f32_16x16x32_f16(a1, bf, acc[j][1], 0, 0, 0);
            }
        }
    }

    // ---- epilogue ----
    if (ATOMIC) {
        #pragma unroll
        for (int j = 0; j < 2; ++j) {
            const float bb = bias[nc[j]] * (1.0f / NSEG);
            #pragma unroll
            for (int m = 0; m < 2; ++m)
                #pragma unroll
                for (int r = 0; r < 4; ++r) {
                    const int t = m * 16 + quad * 4 + r;
                    unsafeAtomicAdd(out + (size_t)t * NDIM + nc[j], acc[j][m][r] + bb);
                }
        }
    } else {
        _Float16* wsp = ws + (size_t)seg * (T_TOK * NDIM);
        #pragma unroll
        for (int j = 0; j < 2; ++j)
            #pragma unroll
            for (int m = 0; m < 2; ++m)
                #pragma unroll
                for (int r = 0; r < 4; ++r) {
                    const int t = m * 16 + quad * 4 + r;
                    wsp[(size_t)t * NDIM + nc[j]] = (_Float16)acc[j][m][r];
                }
    }
}

__global__ __launch_bounds__(256)
void reduce_bias(const _Float16* __restrict__ ws,
                 const float*    __restrict__ bias,
                 float*          __restrict__ out)
{
    const int e = (blockIdx.x * 256 + threadIdx.x) * 8;  // 8 consecutive, one row
    const int n = e % NDIM;
    float sum[8] = {0.f, 0.f, 0.f, 0.f, 0.f, 0.f, 0.f, 0.f};
    #pragma unroll
    for (int s = 0; s < NSEG; ++s) {
        half8 v = *(const half8*)(ws + (size_t)s * (T_TOK * NDIM) + e);
        #pragma unroll
        for (int i = 0; i < 8; ++i) sum[i] += (float)v[i];
    }
    f32x4 o0, o1;
    #pragma unroll
    for (int i = 0; i < 4; ++i) {
        o0[i] = sum[i]     + bias[n + i];
        o1[i] = sum[i + 4] + bias[n + 4 + i];
    }
    *(f32x4*)(out + e)     = o0;
    *(f32x4*)(out + e + 4) = o1;
}

extern "C" void kernel_launch(void* const* d_in, const int* in_sizes, int n_in,
                              void* d_out, int out_size, void* d_ws, size_t ws_size,
                              hipStream_t stream)
{
    const float* x  = (const float*)d_in[0];   // (32, 8192) f32 (fp16 promoted)
    const int* qweight = (const int*)d_in[1];  // (1024, 28672) i32
    const int* qzeros  = (const int*)d_in[2];  // (64, 3584) i32
    const float* sc = (const float*)d_in[3];   // (64, 28672) f32
    const float* bs = (const float*)d_in[4];   // (28672,) f32
    float* out      = (float*)d_out;           // (32, 28672) f32

    const size_t need = (size_t)NSEG * T_TOK * NDIM * sizeof(_Float16);  // 29.4 MB
    if (ws_size >= need) {
        exllama_gemm16<false><<<dim3(NDIM / 128, NSEG), 256, 0, stream>>>(
            qweight, qzeros, sc, x, bs, (_Float16*)d_ws, out);
        reduce_bias<<<(T_TOK * NDIM) / (256 * 8), 256, 0, stream>>>(
            (const _Float16*)d_ws, bs, out);
    } else {
        exllama_gemm16<true><<<dim3(NDIM / 128, NSEG), 256, 0, stream>>>(
            qweight, qzeros, sc, x, bs, nullptr, out);
    }
}